// Round 1
// baseline (19.822 us; speedup 1.0000x reference)
//
#include <hip/hip_runtime.h>

// DKSTE scoring kernel: score[b] = || h0*(s*t0 - d*a*t1) + h1*(d*t0 + s*a*t1) ||_2
// where s=(sign(x)+sign(y))/2, d=(sign(x)-sign(y))/2, a=sign(alpha), per dim.
//
// Layouts (row-major, f32):
//   entity_embedding : (200000, 512, 1, 2)  -> row = 1024 floats (dim*2 + k)
//   relation_embedding: (500, 512, 2)       -> row = 1024 floats
//   alpha_embedding  : (500, 512)           -> row = 512 floats
//
// One 64-lane wave per batch element; 4 waves (256 threads) per block.
// Each lane handles 8 dims via 4x float4 loads (each float4 covers 2 dims
// since K=2 is innermost). Wave shuffle-reduce, lane 0 writes sqrt.

__device__ __forceinline__ float sgn(float x) {
    return (x > 0.f) ? 1.f : ((x < 0.f) ? -1.f : 0.f);
}

__global__ __launch_bounds__(256) void DKSTE_85315230367936_kernel(
    const int* __restrict__ head_idx,
    const int* __restrict__ rel_idx,
    const int* __restrict__ tail_idx,
    const float* __restrict__ ent,
    const float* __restrict__ rel,
    const float* __restrict__ alpha,
    float* __restrict__ out,
    int batch)
{
    const int wave = threadIdx.x >> 6;
    const int lane = threadIdx.x & 63;
    const int b = blockIdx.x * 4 + wave;
    if (b >= batch) return;

    const long long h = head_idx[b];
    const long long t = tail_idx[b];
    const long long r = rel_idx[b];

    const float4* __restrict__ hrow = (const float4*)(ent + h * 1024ll);
    const float4* __restrict__ trow = (const float4*)(ent + t * 1024ll);
    const float4* __restrict__ rrow = (const float4*)(rel + r * 1024ll);
    const float2* __restrict__ arow = (const float2*)(alpha + r * 512ll);

    float acc = 0.f;
#pragma unroll
    for (int j = 0; j < 4; ++j) {
        const int i = lane + 64 * j;      // float4 index; covers dims 2i, 2i+1
        const float4 hv = hrow[i];        // (h0[2i], h1[2i], h0[2i+1], h1[2i+1])
        const float4 tv = trow[i];
        const float4 rv = rrow[i];        // (x[2i], y[2i], x[2i+1], y[2i+1])
        const float2 av = arow[i];        // (a[2i], a[2i+1])

        {   // dim 2i
            const float sx = sgn(rv.x), sy = sgn(rv.y), sa = sgn(av.x);
            const float s = (sx + sy) * 0.5f;
            const float d = (sx - sy) * 0.5f;
            const float sc = hv.x * (s * tv.x - d * sa * tv.y)
                           + hv.y * (d * tv.x + s * sa * tv.y);
            acc = fmaf(sc, sc, acc);
        }
        {   // dim 2i+1
            const float sx = sgn(rv.z), sy = sgn(rv.w), sa = sgn(av.y);
            const float s = (sx + sy) * 0.5f;
            const float d = (sx - sy) * 0.5f;
            const float sc = hv.z * (s * tv.z - d * sa * tv.w)
                           + hv.w * (d * tv.z + s * sa * tv.w);
            acc = fmaf(sc, sc, acc);
        }
    }

    // 64-lane butterfly reduction
#pragma unroll
    for (int off = 32; off; off >>= 1)
        acc += __shfl_xor(acc, off, 64);

    if (lane == 0)
        out[b] = sqrtf(acc);
}

extern "C" void kernel_launch(void* const* d_in, const int* in_sizes, int n_in,
                              void* d_out, int out_size, void* d_ws, size_t ws_size,
                              hipStream_t stream) {
    const int*   head_idx = (const int*)d_in[0];
    const int*   rel_idx  = (const int*)d_in[1];
    const int*   tail_idx = (const int*)d_in[2];
    const float* ent      = (const float*)d_in[3];
    const float* rel      = (const float*)d_in[4];
    const float* alpha    = (const float*)d_in[5];
    float*       out      = (float*)d_out;

    const int batch = in_sizes[0];             // 8192
    const int blocks = (batch + 3) / 4;        // 4 waves (batch elems) per block

    DKSTE_85315230367936_kernel<<<blocks, 256, 0, stream>>>(
        head_idx, rel_idx, tail_idx, ent, rel, alpha, out, batch);
}